// Round 2
// baseline (539.049 us; speedup 1.0000x reference)
//
#include <hip/hip_runtime.h>

// Problem constants
#define NN 4096   // nodes
#define KK 48     // neighbors
#define CC 128    // channels
#define EC 384    // edge context
#define DD 512    // CC + ECTX
#define HH 512    // dense hidden

typedef short bf16x8 __attribute__((ext_vector_type(8)));
typedef float f32x4 __attribute__((ext_vector_type(4)));

__device__ __forceinline__ unsigned short f2bf(float x){
  union { float f; unsigned int u; } c; c.f = x;
  return (unsigned short)((c.u + 0x7fffu + ((c.u >> 16) & 1u)) >> 16);
}

__device__ __forceinline__ bf16x8 pack8(f32x4 a, f32x4 b){
  bf16x8 r;
  r[0]=(short)f2bf(a[0]); r[1]=(short)f2bf(a[1]);
  r[2]=(short)f2bf(a[2]); r[3]=(short)f2bf(a[3]);
  r[4]=(short)f2bf(b[0]); r[5]=(short)f2bf(b[1]);
  r[6]=(short)f2bf(b[2]); r[7]=(short)f2bf(b[3]);
  return r;
}

// tanh-form gelu via hardware exp: |err vs exact erf-gelu| ~1e-3, well under the
// 0.0906 output threshold. Robust at +-inf of expf.
__device__ __forceinline__ float gelu_f(float x){
  float s = 1.5957691216057308f * (x + 0.044715f*x*x*x);  // 2*0.79788456*(x+0.044715x^3)
  float e = __expf(s);
  float t = 1.0f - 2.0f/(e + 1.0f);
  return 0.5f*x*(1.0f + t);
}

// ---------------- weight fp32 -> bf16 conversion (one pass over 229376 elems) ----
__global__ void cvt_kernel(const float* __restrict__ W1, const float* __restrict__ W2,
                           const float* __restrict__ W3, const float* __restrict__ Wd1,
                           const float* __restrict__ Wd2, unsigned short* __restrict__ o){
  int i = blockIdx.x*256 + threadIdx.x;   // grid sized exactly 896*256 = 229376
  float v;
  if      (i <  65536) v = W1[i];
  else if (i <  81920) v = W2[i-65536];
  else if (i <  98304) v = W3[i-81920];
  else if (i < 163840) v = Wd1[i-98304];
  else                 v = Wd2[i-163840];
  o[i] = f2bf(v);
}

// ---------------- message MLP + aggregation -------------------------------------
// block = 256 threads (4 waves: 2 M-waves x 2 N-waves), 2 nodes (96 edge rows)
__global__ __launch_bounds__(256, 2) void msg_kernel(
    const float* __restrict__ nodef, const float* __restrict__ edgef,
    const float* __restrict__ attn,
    const unsigned short* __restrict__ W1b, const float* __restrict__ b1,
    const unsigned short* __restrict__ W2b, const float* __restrict__ b2,
    const unsigned short* __restrict__ W3b, const float* __restrict__ b3,
    float* __restrict__ x1)
{
  __shared__ __attribute__((aligned(16))) unsigned short H1[96][136]; // pad: 2-way max
  __shared__ __attribute__((aligned(16))) unsigned short H2[96][136];

  const int tid  = threadIdx.x;
  const int lane = tid & 63;
  const int wid  = tid >> 6;
  const int wm   = wid & 1;       // M-half (node within block)
  const int wn   = wid >> 1;      // N-half (64 cols)
  const int l15  = lane & 15;
  const int lg   = lane >> 4;     // 0..3
  const int lg8  = lg*8;
  const int node = blockIdx.x*2 + wm;
  const int colb = wn*64;

  const float* nrow = nodef + (size_t)node*CC;
  const float* erow[3];
  #pragma unroll
  for (int mt=0; mt<3; ++mt)
    erow[mt] = edgef + ((size_t)node*KK + (mt*16 + l15))*EC;

  f32x4 acc[3][4];
  #pragma unroll
  for (int mt=0; mt<3; ++mt)
    #pragma unroll
    for (int nt=0; nt<4; ++nt) acc[mt][nt] = (f32x4){0.f,0.f,0.f,0.f};

  // ---- GEMM1: A(96x512) direct-from-global (fp32 -> bf16 pack), B = W1b (L2) ----
  bf16x8 aC[3], bC[4], aN[3], bN[4];
  #pragma unroll
  for (int nt=0; nt<4; ++nt)
    bC[nt] = *(const bf16x8*)(W1b + (size_t)(colb + nt*16 + l15)*DD + lg8);
  #pragma unroll
  for (int mt=0; mt<3; ++mt){
    const float* s = nrow + lg8;                       // k0=0 < 128: node part (broadcast rows)
    aC[mt] = pack8(*(const f32x4*)s, *(const f32x4*)(s+4));
  }

  #pragma unroll
  for (int ks=0; ks<16; ++ks){
    if (ks < 15){
      const int k1 = (ks+1)*32;
      #pragma unroll
      for (int nt=0; nt<4; ++nt)
        bN[nt] = *(const bf16x8*)(W1b + (size_t)(colb + nt*16 + l15)*DD + k1 + lg8);
      #pragma unroll
      for (int mt=0; mt<3; ++mt){
        const float* s = (k1 < CC) ? (nrow + k1 + lg8) : (erow[mt] + (k1 - CC) + lg8);
        aN[mt] = pack8(*(const f32x4*)s, *(const f32x4*)(s+4));
      }
    }
    #pragma unroll
    for (int mt=0; mt<3; ++mt)
      #pragma unroll
      for (int nt=0; nt<4; ++nt)
        acc[mt][nt] = __builtin_amdgcn_mfma_f32_16x16x32_bf16(aC[mt], bC[nt], acc[mt][nt], 0,0,0);
    #pragma unroll
    for (int mt=0; mt<3; ++mt) aC[mt] = aN[mt];
    #pragma unroll
    for (int nt=0; nt<4; ++nt) bC[nt] = bN[nt];
  }

  // epilogue 1: + b1, gelu, -> H1 (bf16)
  #pragma unroll
  for (int nt=0; nt<4; ++nt){
    const int c = colb + nt*16 + l15;
    const float bb = b1[c];
    #pragma unroll
    for (int mt=0; mt<3; ++mt){
      const int r0 = wm*48 + mt*16 + lg*4;
      #pragma unroll
      for (int j=0; j<4; ++j)
        H1[r0+j][c] = f2bf(gelu_f(acc[mt][nt][j] + bb));
    }
  }
  __syncthreads();

  // ---- GEMM2: (96x128) x W2^T, A from LDS ----
  f32x4 a2[3][4];
  #pragma unroll
  for (int mt=0; mt<3; ++mt)
    #pragma unroll
    for (int nt=0; nt<4; ++nt) a2[mt][nt] = (f32x4){0.f,0.f,0.f,0.f};

  #pragma unroll
  for (int ks=0; ks<4; ++ks){
    const int k0 = ks*32;
    bf16x8 bf_[4], af_[3];
    #pragma unroll
    for (int nt=0; nt<4; ++nt)
      bf_[nt] = *(const bf16x8*)(W2b + (size_t)(colb + nt*16 + l15)*CC + k0 + lg8);
    #pragma unroll
    for (int mt=0; mt<3; ++mt)
      af_[mt] = *(const bf16x8*)&H1[wm*48 + mt*16 + l15][k0 + lg8];
    #pragma unroll
    for (int mt=0; mt<3; ++mt)
      #pragma unroll
      for (int nt=0; nt<4; ++nt)
        a2[mt][nt] = __builtin_amdgcn_mfma_f32_16x16x32_bf16(af_[mt], bf_[nt], a2[mt][nt], 0,0,0);
  }

  #pragma unroll
  for (int nt=0; nt<4; ++nt){
    const int c = colb + nt*16 + l15;
    const float bb = b2[c];
    #pragma unroll
    for (int mt=0; mt<3; ++mt){
      const int r0 = wm*48 + mt*16 + lg*4;
      #pragma unroll
      for (int j=0; j<4; ++j)
        H2[r0+j][c] = f2bf(gelu_f(a2[mt][nt][j] + bb));
    }
  }
  __syncthreads();

  // ---- GEMM3: (96x128) x W3^T (linear out) ----
  f32x4 a3[3][4];
  #pragma unroll
  for (int mt=0; mt<3; ++mt)
    #pragma unroll
    for (int nt=0; nt<4; ++nt) a3[mt][nt] = (f32x4){0.f,0.f,0.f,0.f};

  #pragma unroll
  for (int ks=0; ks<4; ++ks){
    const int k0 = ks*32;
    bf16x8 bf_[4], af_[3];
    #pragma unroll
    for (int nt=0; nt<4; ++nt)
      bf_[nt] = *(const bf16x8*)(W3b + (size_t)(colb + nt*16 + l15)*CC + k0 + lg8);
    #pragma unroll
    for (int mt=0; mt<3; ++mt)
      af_[mt] = *(const bf16x8*)&H2[wm*48 + mt*16 + l15][k0 + lg8];
    #pragma unroll
    for (int mt=0; mt<3; ++mt)
      #pragma unroll
      for (int nt=0; nt<4; ++nt)
        a3[mt][nt] = __builtin_amdgcn_mfma_f32_16x16x32_bf16(af_[mt], bf_[nt], a3[mt][nt], 0,0,0);
  }

  // aggregation: all rows of this wave's frags belong to `node`; cols disjoint per wave.
  float av[3][4];
  #pragma unroll
  for (int mt=0; mt<3; ++mt)
    #pragma unroll
    for (int j=0; j<4; ++j)
      av[mt][j] = attn[(size_t)node*KK + mt*16 + lg*4 + j];

  #pragma unroll
  for (int nt=0; nt<4; ++nt){
    const int c = colb + nt*16 + l15;
    const float bb = b3[c];
    float t = 0.f;
    #pragma unroll
    for (int mt=0; mt<3; ++mt)
      #pragma unroll
      for (int j=0; j<4; ++j)
        t += (a3[mt][nt][j] + bb) * av[mt][j];
    t += __shfl_xor(t, 16, 64);   // sum over the 4 row-groups
    t += __shfl_xor(t, 32, 64);
    if (lg == 0)
      x1[(size_t)node*CC + c] = nodef[(size_t)node*CC + c] + t*(1.0f/30.0f);
  }
}

// ---------------- LN1 -> dense MLP -> residual -> LN2 -> mask -------------------
// block = 256 threads (4 waves), 16 nodes
__global__ __launch_bounds__(256, 2) void post_kernel(
    const float* __restrict__ x1, const float* __restrict__ mask,
    const float* __restrict__ g1, const float* __restrict__ be1,
    const unsigned short* __restrict__ Wd1b, const float* __restrict__ bd1,
    const unsigned short* __restrict__ Wd2b, const float* __restrict__ bd2,
    const float* __restrict__ g2, const float* __restrict__ be2,
    float* __restrict__ out)
{
  __shared__ __attribute__((aligned(16))) unsigned short xlnB[16][136];
  __shared__ __attribute__((aligned(16))) float          xlnF[16][132];
  __shared__ __attribute__((aligned(16))) unsigned short Hb[16][520];
  __shared__ __attribute__((aligned(16))) float          x2s[16][132];

  const int tid  = threadIdx.x;
  const int lane = tid & 63;
  const int wid  = tid >> 6;
  const int l15  = lane & 15;
  const int lg   = lane >> 4;
  const int lg8  = lg*8;
  const int n0   = blockIdx.x * 16;

  // ---- LN1: 16 threads per node, 8 cols each ----
  {
    const int nl = tid >> 4;
    const int s  = tid & 15;
    const float* row = x1 + (size_t)(n0+nl)*CC + s*8;
    f32x4 a = *(const f32x4*)row;
    f32x4 b = *(const f32x4*)(row+4);
    float sm = (a[0]+a[1])+(a[2]+a[3]) + (b[0]+b[1])+(b[2]+b[3]);
    float sq = a[0]*a[0]+a[1]*a[1]+a[2]*a[2]+a[3]*a[3]
             + b[0]*b[0]+b[1]*b[1]+b[2]*b[2]+b[3]*b[3];
    sm += __shfl_xor(sm,1,64); sq += __shfl_xor(sq,1,64);
    sm += __shfl_xor(sm,2,64); sq += __shfl_xor(sq,2,64);
    sm += __shfl_xor(sm,4,64); sq += __shfl_xor(sq,4,64);
    sm += __shfl_xor(sm,8,64); sq += __shfl_xor(sq,8,64);
    const float mu = sm*(1.f/128.f);
    const float rs = rsqrtf(sq*(1.f/128.f) - mu*mu + 1e-5f);
    #pragma unroll
    for (int j=0; j<8; ++j){
      const int c = s*8+j;
      float xv = (j<4) ? a[j] : b[j-4];
      float y = (xv-mu)*rs*g1[c] + be1[c];
      xlnF[nl][c] = y;
      xlnB[nl][c] = f2bf(y);
    }
  }
  __syncthreads();

  // ---- dense layer 1: (16x128) @ Wd1^T -> 16x512, gelu ----
  f32x4 a1[8];
  #pragma unroll
  for (int nt=0; nt<8; ++nt) a1[nt] = (f32x4){0.f,0.f,0.f,0.f};
  #pragma unroll
  for (int ks=0; ks<4; ++ks){
    const int k0 = ks*32;
    bf16x8 af = *(const bf16x8*)&xlnB[l15][k0 + lg8];
    #pragma unroll
    for (int nt=0; nt<8; ++nt){
      const int h = wid*128 + nt*16 + l15;
      bf16x8 bf_ = *(const bf16x8*)(Wd1b + (size_t)h*CC + k0 + lg8);
      a1[nt] = __builtin_amdgcn_mfma_f32_16x16x32_bf16(af, bf_, a1[nt], 0,0,0);
    }
  }
  #pragma unroll
  for (int nt=0; nt<8; ++nt){
    const int h = wid*128 + nt*16 + l15;
    const float bb = bd1[h];
    #pragma unroll
    for (int j=0; j<4; ++j)
      Hb[lg*4+j][h] = f2bf(gelu_f(a1[nt][j] + bb));
  }
  __syncthreads();

  // ---- dense layer 2: (16x512) @ Wd2^T -> 16x128, + residual ----
  f32x4 a2[2];
  #pragma unroll
  for (int nt=0; nt<2; ++nt) a2[nt] = (f32x4){0.f,0.f,0.f,0.f};
  #pragma unroll
  for (int ks=0; ks<16; ++ks){
    const int k0 = ks*32;
    bf16x8 af = *(const bf16x8*)&Hb[l15][k0 + lg8];
    #pragma unroll
    for (int nt=0; nt<2; ++nt){
      const int c = wid*32 + nt*16 + l15;
      bf16x8 bf_ = *(const bf16x8*)(Wd2b + (size_t)c*HH + k0 + lg8);
      a2[nt] = __builtin_amdgcn_mfma_f32_16x16x32_bf16(af, bf_, a2[nt], 0,0,0);
    }
  }
  #pragma unroll
  for (int nt=0; nt<2; ++nt){
    const int c = wid*32 + nt*16 + l15;
    const float bb = bd2[c];
    #pragma unroll
    for (int j=0; j<4; ++j){
      const int r = lg*4 + j;
      x2s[r][c] = xlnF[r][c] + a2[nt][j] + bb;
    }
  }
  __syncthreads();

  // ---- LN2 + mask + store ----
  {
    const int nl = tid >> 4;
    const int s  = tid & 15;
    float xv[8];
    float sm = 0.f, sq = 0.f;
    #pragma unroll
    for (int j=0; j<8; ++j){ xv[j] = x2s[nl][s*8+j]; sm += xv[j]; sq += xv[j]*xv[j]; }
    sm += __shfl_xor(sm,1,64); sq += __shfl_xor(sq,1,64);
    sm += __shfl_xor(sm,2,64); sq += __shfl_xor(sq,2,64);
    sm += __shfl_xor(sm,4,64); sq += __shfl_xor(sq,4,64);
    sm += __shfl_xor(sm,8,64); sq += __shfl_xor(sq,8,64);
    const float mu = sm*(1.f/128.f);
    const float rs = rsqrtf(sq*(1.f/128.f) - mu*mu + 1e-5f);
    const float mk = mask[n0+nl];
    f32x4 o0, o1;
    #pragma unroll
    for (int j=0; j<8; ++j){
      const int c = s*8+j;
      float y = (xv[j]-mu)*rs*g2[c] + be2[c];
      if (j < 4) o0[j] = mk*y; else o1[j-4] = mk*y;
    }
    float* orow = out + (size_t)(n0+nl)*CC + s*8;
    *(f32x4*)orow     = o0;
    *(f32x4*)(orow+4) = o1;
  }
}

extern "C" void kernel_launch(void* const* d_in, const int* in_sizes, int n_in,
                              void* d_out, int out_size, void* d_ws, size_t ws_size,
                              hipStream_t stream)
{
  (void)in_sizes; (void)n_in; (void)out_size; (void)ws_size;

  const float* nodef = (const float*)d_in[0];
  const float* edgef = (const float*)d_in[1];
  const float* mask  = (const float*)d_in[2];
  const float* attn  = (const float*)d_in[3];
  const float* W_m1  = (const float*)d_in[4];
  const float* b_m1  = (const float*)d_in[5];
  const float* W_m2  = (const float*)d_in[6];
  const float* b_m2  = (const float*)d_in[7];
  const float* W_m3  = (const float*)d_in[8];
  const float* b_m3  = (const float*)d_in[9];
  const float* g1    = (const float*)d_in[10];
  const float* be1   = (const float*)d_in[11];
  const float* W_d1  = (const float*)d_in[12];
  const float* b_d1  = (const float*)d_in[13];
  const float* W_d2  = (const float*)d_in[14];
  const float* b_d2  = (const float*)d_in[15];
  const float* g2    = (const float*)d_in[16];
  const float* be2   = (const float*)d_in[17];

  // ws layout (elements of ushort): W1b 0..65536, W2b ..81920, W3b ..98304,
  // Wd1b ..163840, Wd2b ..229376; then x1 (fp32, 524288) at byte 458752.
  unsigned short* wsb  = (unsigned short*)d_ws;
  unsigned short* W1b  = wsb;
  unsigned short* W2b  = wsb + 65536;
  unsigned short* W3b  = wsb + 81920;
  unsigned short* Wd1b = wsb + 98304;
  unsigned short* Wd2b = wsb + 163840;
  float* x1 = (float*)((char*)d_ws + 458752);

  cvt_kernel<<<896, 256, 0, stream>>>(W_m1, W_m2, W_m3, W_d1, W_d2, wsb);
  msg_kernel<<<2048, 256, 0, stream>>>(nodef, edgef, attn,
                                       W1b, b_m1, W2b, b_m2, W3b, b_m3, x1);
  post_kernel<<<256, 256, 0, stream>>>(x1, mask, g1, be1, Wd1b, b_d1,
                                       Wd2b, b_d2, g2, be2, (float*)d_out);
}